// Round 13
// baseline (948.721 us; speedup 1.0000x reference)
//
#include <hip/hip_runtime.h>

// GCN 3-layer, R13. Build identical to R11/R12. fused_l2l3 = R10 edge loop
// (readlane, dynamic trip, no prefetch) + batched stage-B W2 matmul:
// a2 for 8 nodes banked in LDS, W2 column reads amortized 8x (conflict-free
// stride-1 pattern, same as R10's proven epilogue).

#define BKSH 8                      // 256 nodes per bucket
#define EPB  4096                   // edges per scatter block

__device__ __forceinline__ float rlane(float v, int l) {
    return __int_as_float(__builtin_amdgcn_readlane(__float_as_int(v), l));
}
__device__ __forceinline__ int rfl(int v) { return __builtin_amdgcn_readfirstlane(v); }

// ---- per-block bucket histogram ----
__global__ void bhist(const int* __restrict__ dst, int* __restrict__ ghist,
                      int E, int NBK, int BLK) {
    __shared__ int h[512];
    int t = threadIdx.x, b = blockIdx.x;
    for (int i = t; i < NBK; i += 256) h[i] = 0;
    __syncthreads();
    int base = b * EPB;
    #pragma unroll
    for (int i = 0; i < 16; ++i) {
        int e = base + i * 256 + t;
        if (e < E) atomicAdd(&h[dst[e] >> BKSH], 1);
    }
    __syncthreads();
    for (int i = t; i < NBK; i += 256) ghist[(size_t)i * BLK + b] = h[i];
}

// ---- exclusive scan phases (block-sum add folded into readers) ----
__global__ void gscan1(const int* __restrict__ in, int* __restrict__ out,
                       int* __restrict__ bsums, int M) {
    __shared__ int tmp[256];
    int i = blockIdx.x * 256 + threadIdx.x;
    int v = (i < M) ? in[i] : 0;
    tmp[threadIdx.x] = v; __syncthreads();
    for (int off = 1; off < 256; off <<= 1) {
        int t = (threadIdx.x >= off) ? tmp[threadIdx.x - off] : 0;
        __syncthreads();
        tmp[threadIdx.x] += t;
        __syncthreads();
    }
    if (i < M) out[i] = tmp[threadIdx.x] - v;
    if (threadIdx.x == 255) bsums[blockIdx.x] = tmp[255];
}

__global__ void gscan2(int* __restrict__ bsums, int nb) {   // 1 block, 1024 thr
    __shared__ int tmp[1024];
    int v = (threadIdx.x < nb) ? bsums[threadIdx.x] : 0;
    tmp[threadIdx.x] = v; __syncthreads();
    for (int off = 1; off < 1024; off <<= 1) {
        int t = (threadIdx.x >= off) ? tmp[threadIdx.x - off] : 0;
        __syncthreads();
        tmp[threadIdx.x] += t;
        __syncthreads();
    }
    if (threadIdx.x < nb) bsums[threadIdx.x] = tmp[threadIdx.x] - v;
}

// ---- scatter edges into bucket-sorted tmp (offsets = goff + gbsums) ----
__global__ void bscatter(const int* __restrict__ src, const int* __restrict__ dst,
                         const int* __restrict__ goff, const int* __restrict__ gbsums,
                         uint2* __restrict__ tmp, int E, int NBK, int BLK) {
    __shared__ int off[512];
    int t = threadIdx.x, b = blockIdx.x;
    for (int i = t; i < NBK; i += 256) {
        size_t m = (size_t)i * BLK + b;
        off[i] = goff[m] + gbsums[m >> 8];
    }
    __syncthreads();
    int base = b * EPB;
    #pragma unroll
    for (int i = 0; i < 16; ++i) {
        int e = base + i * 256 + t;
        if (e < E) {
            int d = dst[e];
            int p = atomicAdd(&off[d >> BKSH], 1);   // LDS-local
            tmp[p] = make_uint2((unsigned)src[e], (unsigned)d);
        }
    }
}

// ---- per-bucket: count + LDS scan -> rowptr + dinv ----
__global__ void bucketA(const uint2* __restrict__ tmp, const int* __restrict__ goff,
                        const int* __restrict__ gbsums, int* __restrict__ rowptr,
                        float* __restrict__ dinv, int N, int NBK, int BLK, int E) {
    __shared__ int lc[256], sc[256];
    int b = blockIdx.x, t = threadIdx.x;
    lc[t] = 0; __syncthreads();
    size_t m0 = (size_t)b * BLK;
    int p0 = goff[m0] + gbsums[m0 >> 8];
    int p1 = E;
    if (b + 1 < NBK) { size_t m1 = (size_t)(b + 1) * BLK; p1 = goff[m1] + gbsums[m1 >> 8]; }
    for (int p = p0 + t; p < p1; p += 256) atomicAdd(&lc[tmp[p].y & 255], 1);
    __syncthreads();
    int v = lc[t];
    sc[t] = v; __syncthreads();
    for (int off = 1; off < 256; off <<= 1) {
        int tv = (t >= off) ? sc[t - off] : 0;
        __syncthreads();
        sc[t] += tv;
        __syncthreads();
    }
    int node = (b << BKSH) + t;
    if (node < N) {
        rowptr[node] = p0 + (sc[t] - v);
        dinv[node]   = rsqrtf((float)(v + 1));
    }
    if (b == 0 && t == 0) rowptr[N] = E;
}

// ---- place edges (dense window) + fused layer-1 aggregation ----
__global__ void fillB(const uint2* __restrict__ tmp, const int* __restrict__ goff,
                      const int* __restrict__ gbsums, const int* __restrict__ rowptr,
                      const float* __restrict__ dinv, const float* __restrict__ x,
                      float2* __restrict__ ew, float4* __restrict__ a1,
                      int N, int NBK, int BLK, int E) {
    __shared__ int   lfill[256];
    __shared__ int   rbase[257];
    __shared__ float ldv[256];
    int b = blockIdx.x, t = threadIdx.x;
    int node0 = b << BKSH;
    lfill[t] = 0;
    int node = node0 + t;
    rbase[t] = rowptr[min(node, N)];
    ldv[t]   = dinv[min(node, N - 1)];
    if (t == 0) rbase[256] = rowptr[min(node0 + 256, N)];
    __syncthreads();
    size_t m0 = (size_t)b * BLK;
    int p0 = goff[m0] + gbsums[m0 >> 8];
    int p1 = E;
    if (b + 1 < NBK) { size_t m1 = (size_t)(b + 1) * BLK; p1 = goff[m1] + gbsums[m1 >> 8]; }
    for (int p = p0 + t; p < p1; p += 256) {
        uint2 e = tmp[p];
        int s = (int)e.x, dl = (int)(e.y & 255);
        float w = dinv[s] * ldv[dl];
        int pos = rbase[dl] + atomicAdd(&lfill[dl], 1);
        ew[pos] = make_float2(__int_as_float(s), w);
    }
    __syncthreads();
    // fused agg3: 16 lane-groups sweep the bucket's 256 nodes (ew L2-hot)
    int grp = t >> 4, sub = t & 15;
    for (int ni = grp; ni < 256; ni += 16) {
        int n = node0 + ni;
        if (n >= N) break;
        int q0 = rbase[ni], q1 = rbase[ni + 1];
        float ax = 0.f, ay = 0.f, az = 0.f;
        for (int p = q0 + sub; p < q1; p += 16) {
            float2 e = ew[p];
            int s = __float_as_int(e.x);
            ax = fmaf(e.y, x[s*3+0], ax);
            ay = fmaf(e.y, x[s*3+1], ay);
            az = fmaf(e.y, x[s*3+2], az);
        }
        #pragma unroll
        for (int off = 8; off; off >>= 1) {
            ax += __shfl_down(ax, off, 16);
            ay += __shfl_down(ay, off, 16);
            az += __shfl_down(az, off, 16);
        }
        if (sub == 0) {
            float dv = ldv[ni], sw = dv * dv;
            a1[n] = make_float4(fmaf(sw, x[n*3+0], ax),
                                fmaf(sw, x[n*3+1], ay),
                                fmaf(sw, x[n*3+2], az), sw);
        }
    }
}

// wc[k] = W3[k][:] @ Wh; wc[64] = b3 @ Wh + bh
__global__ void fold_head(const float* __restrict__ W3, const float* __restrict__ b3,
                          const float* __restrict__ Wh, const float* __restrict__ bh,
                          float* __restrict__ wc) {
    int k = threadIdx.x;              // 64
    float acc = 0.0f;
    for (int f = 0; f < 64; f++) acc += W3[k*64+f] * Wh[f];
    wc[k] = acc;
    if (k == 0) {
        float bb = bh[0];
        for (int f = 0; f < 64; f++) bb += b3[f] * Wh[f];
        wc[64] = bb;
    }
}

// z[n] = relu( (S relu(a1@W1+b1))[n] @ W2 + b2 ) @ wc
__global__ void fused_l2l3(const float2* __restrict__ ew, const int* __restrict__ rowptr,
                           const float4* __restrict__ a1, const float* __restrict__ W1,
                           const float* __restrict__ b1, const float* __restrict__ W2,
                           const float* __restrict__ b2, const float* __restrict__ wc,
                           float* __restrict__ z, int N, int E) {
    __shared__ float Wl[64*64];
    __shared__ float a2all[4][8][64];
    const int tid = threadIdx.x;
    for (int i = tid; i < 4096; i += 256) Wl[i] = W2[i];
    const int lane = tid & 63;
    const int wv   = tid >> 6;
    const float w10 = W1[lane], w11 = W1[64+lane], w12 = W1[128+lane];
    const float b1f = b1[lane], b2f = b2[lane], wcf = wc[lane];
    const int NPW = 8;
    const int n0 = (blockIdx.x * 4 + wv) * NPW;
    int   rpl = rowptr[min(n0 + lane, N)];         // lanes 0..8 used
    float4 sg = a1[min(n0 + lane, N - 1)];         // lanes 0..7 used (self terms)
    __syncthreads();
    if (n0 < N) {
        for (int cur = 0; cur < NPW; ++cur) {
            int n = n0 + cur;
            if (n >= N) break;
            int p0 = rfl(__shfl(rpl, cur));
            int p1 = rfl(__shfl(rpl, cur + 1));
            float sx = rlane(sg.x, cur), sy = rlane(sg.y, cur);
            float sz2 = rlane(sg.z, cur), sw = rlane(sg.w, cur);
            float ts = fmaf(sz2, w12, fmaf(sy, w11, fmaf(sx, w10, b1f)));
            float acc = sw * fmaxf(ts, 0.f);
            for (int pc = p0; pc < p1; pc += 64) {
                int pidx = pc + lane; if (pidx >= p1) pidx = p1 - 1;
                float2 e  = ew[pidx];                  // coalesced per-lane
                float4 g  = a1[__float_as_int(e.x)];   // 64-wide gather
                int m = p1 - pc; if (m > 64) m = 64;   // uniform trip (SGPR)
                int j = 0;
                for (; j + 3 < m; j += 4) {
                    #pragma unroll
                    for (int u = 0; u < 4; ++u) {
                        float ex = rlane(g.x, j+u), ey = rlane(g.y, j+u);
                        float ez = rlane(g.z, j+u), ww = rlane(e.y, j+u);
                        float tt = fmaf(ez, w12, fmaf(ey, w11, fmaf(ex, w10, b1f)));
                        acc = fmaf(ww, fmaxf(tt, 0.f), acc);
                    }
                }
                for (; j < m; ++j) {
                    float ex = rlane(g.x, j), ey = rlane(g.y, j);
                    float ez = rlane(g.z, j), ww = rlane(e.y, j);
                    float tt = fmaf(ez, w12, fmaf(ey, w11, fmaf(ex, w10, b1f)));
                    acc = fmaf(ww, fmaxf(tt, 0.f), acc);
                }
            }
            a2all[wv][cur][lane] = acc;                // wave-private LDS
        }
        // ---- stage B: batched W2 matmul for the wave's 8 nodes ----
        int nv = N - n0; if (nv > 8) nv = 8;           // valid nodes (SGPR)
        float h0 = b2f, h1 = b2f, h2 = b2f, h3 = b2f;
        float h4 = b2f, h5 = b2f, h6 = b2f, h7 = b2f;
        const float4* a24 = (const float4*)&a2all[wv][0][0];   // [8][16] float4
        #pragma unroll
        for (int k4 = 0; k4 < 16; ++k4) {
            // W2 column slice: proven conflict-free stride-1 reads (R10 pattern)
            float wk0 = Wl[(4*k4+0)*64 + lane];
            float wk1 = Wl[(4*k4+1)*64 + lane];
            float wk2 = Wl[(4*k4+2)*64 + lane];
            float wk3 = Wl[(4*k4+3)*64 + lane];
            float4 a0 = a24[0*16 + k4], a1v = a24[1*16 + k4];
            float4 a2 = a24[2*16 + k4], a3v = a24[3*16 + k4];
            float4 a4 = a24[4*16 + k4], a5v = a24[5*16 + k4];
            float4 a6 = a24[6*16 + k4], a7v = a24[7*16 + k4];
            h0 = fmaf(a0.x, wk0, h0); h0 = fmaf(a0.y, wk1, h0);
            h0 = fmaf(a0.z, wk2, h0); h0 = fmaf(a0.w, wk3, h0);
            h1 = fmaf(a1v.x, wk0, h1); h1 = fmaf(a1v.y, wk1, h1);
            h1 = fmaf(a1v.z, wk2, h1); h1 = fmaf(a1v.w, wk3, h1);
            h2 = fmaf(a2.x, wk0, h2); h2 = fmaf(a2.y, wk1, h2);
            h2 = fmaf(a2.z, wk2, h2); h2 = fmaf(a2.w, wk3, h2);
            h3 = fmaf(a3v.x, wk0, h3); h3 = fmaf(a3v.y, wk1, h3);
            h3 = fmaf(a3v.z, wk2, h3); h3 = fmaf(a3v.w, wk3, h3);
            h4 = fmaf(a4.x, wk0, h4); h4 = fmaf(a4.y, wk1, h4);
            h4 = fmaf(a4.z, wk2, h4); h4 = fmaf(a4.w, wk3, h4);
            h5 = fmaf(a5v.x, wk0, h5); h5 = fmaf(a5v.y, wk1, h5);
            h5 = fmaf(a5v.z, wk2, h5); h5 = fmaf(a5v.w, wk3, h5);
            h6 = fmaf(a6.x, wk0, h6); h6 = fmaf(a6.y, wk1, h6);
            h6 = fmaf(a6.z, wk2, h6); h6 = fmaf(a6.w, wk3, h6);
            h7 = fmaf(a7v.x, wk0, h7); h7 = fmaf(a7v.y, wk1, h7);
            h7 = fmaf(a7v.z, wk2, h7); h7 = fmaf(a7v.w, wk3, h7);
        }
        float hs[8] = {h0, h1, h2, h3, h4, h5, h6, h7};
        #pragma unroll
        for (int i = 0; i < 8; ++i) {
            if (i >= nv) break;                        // uniform
            float v = fmaxf(hs[i], 0.f) * wcf;
            #pragma unroll
            for (int off = 32; off; off >>= 1) v += __shfl_down(v, off);
            if (lane == 0) z[n0 + i] = v;
        }
    }
}

// logits[n] = dinv^2 z[n] + sum_e w z[s] + c; 16-lane group per node
__global__ void final_wave(const float* __restrict__ z, const float2* __restrict__ ew,
                           const int* __restrict__ rowptr, const float* __restrict__ dinv,
                           const float* __restrict__ wc, float* __restrict__ out, int N) {
    int g   = (blockIdx.x * blockDim.x + threadIdx.x) >> 4;
    int sub = threadIdx.x & 15;
    if (g >= N) return;
    int p0 = rowptr[g], p1 = rowptr[g+1];
    float acc = 0.f;
    for (int p = p0 + sub; p < p1; p += 16) {
        float2 e = ew[p];
        acc = fmaf(e.y, z[__float_as_int(e.x)], acc);
    }
    #pragma unroll
    for (int off = 8; off; off >>= 1) acc += __shfl_down(acc, off, 16);
    if (sub == 0) {
        float dv = dinv[g];
        out[g] = fmaf(dv * dv, z[g], acc) + wc[64];
    }
}

extern "C" void kernel_launch(void* const* d_in, const int* in_sizes, int n_in,
                              void* d_out, int out_size, void* d_ws, size_t ws_size,
                              hipStream_t stream) {
    const float* x   = (const float*)d_in[0];
    const int*   ei  = (const int*)d_in[1];
    const float* W1  = (const float*)d_in[2];
    const float* b1  = (const float*)d_in[3];
    const float* W2  = (const float*)d_in[4];
    const float* b2  = (const float*)d_in[5];
    const float* W3  = (const float*)d_in[6];
    const float* b3  = (const float*)d_in[7];
    const float* Wh  = (const float*)d_in[8];
    const float* bh  = (const float*)d_in[9];
    float* logits = (float*)d_out;

    const int N = in_sizes[0] / 3;
    const int E = in_sizes[1] / 2;
    const int* src = ei;
    const int* dst = ei + E;

    const int NBK = (N + 255) >> BKSH;            // 391 buckets
    const int BLK = (E + EPB - 1) / EPB;          // 391 scatter blocks
    const int M   = NBK * BLK;

    float* base = (float*)d_ws;
    size_t o = 0;
    float*  dinv   = base + o; o += (size_t)N;
    o = (o + 3) & ~(size_t)3;
    float4* a1     = (float4*)(base + o); o += (size_t)4*N;
    int*    rowptr = (int*)(base + o); o += (size_t)N + 1;
    int*    gbsums = (int*)(base + o); o += 1024;
    o = (o + 1) & ~(size_t)1;
    float2* ew     = (float2*)(base + o); o += (size_t)2*E;
    uint2*  tmpb   = (uint2*)(base + o); o += (size_t)2*E;
    float*  zbuf   = base + o; o += (size_t)N;
    float*  wc     = base + o; o += 65;
    int*    ghist  = (int*)(base + o); o += (size_t)M;
    int*    goff   = (int*)(base + o); o += (size_t)M;

    const int BS = 256;
    int gM   = (M + BS - 1) / BS;
    int g16  = ((size_t)N * 16 + BS - 1) / BS;
    int gFU  = (N + 31) / 32;

    bhist    <<<BLK, BS, 0, stream>>>(dst, ghist, E, NBK, BLK);
    gscan1   <<<gM,  BS, 0, stream>>>(ghist, goff, gbsums, M);
    gscan2   <<<1, 1024, 0, stream>>>(gbsums, gM);
    bscatter <<<BLK, BS, 0, stream>>>(src, dst, goff, gbsums, tmpb, E, NBK, BLK);
    bucketA  <<<NBK, BS, 0, stream>>>(tmpb, goff, gbsums, rowptr, dinv, N, NBK, BLK, E);
    fillB    <<<NBK, BS, 0, stream>>>(tmpb, goff, gbsums, rowptr, dinv, x, ew, a1, N, NBK, BLK, E);

    fold_head  <<<1, 64, 0, stream>>>(W3, b3, Wh, bh, wc);
    fused_l2l3 <<<gFU, BS, 0, stream>>>(ew, rowptr, a1, W1, b1, W2, b2, wc, zbuf, N, E);
    final_wave <<<g16, BS, 0, stream>>>(zbuf, ew, rowptr, dinv, wc, logits, N);
}

// Round 14
// 495.088 us; speedup vs baseline: 1.9163x; 1.9163x over previous
//
#include <hip/hip_runtime.h>

// GCN 3-layer, R14. Build identical to R11. fused_l2l3: R10 structure +
//  (1) LDS payload broadcast: per chunk ds_write_b128 {a1[s].xyz,w}, consume
//      via uniform ds_read_b128 (replaces 4 readlanes/edge);
//  (2) 4-node batched W2 epilogue, NAMED scalars only (no local arrays —
//      R12/R13 died from hs[8] scratch demotion, 2.5GB scratch round-trip).

#define BKSH 8                      // 256 nodes per bucket
#define EPB  4096                   // edges per scatter block

__device__ __forceinline__ float rlane(float v, int l) {
    return __int_as_float(__builtin_amdgcn_readlane(__float_as_int(v), l));
}
__device__ __forceinline__ int rfl(int v) { return __builtin_amdgcn_readfirstlane(v); }

// ---- per-block bucket histogram ----
__global__ void bhist(const int* __restrict__ dst, int* __restrict__ ghist,
                      int E, int NBK, int BLK) {
    __shared__ int h[512];
    int t = threadIdx.x, b = blockIdx.x;
    for (int i = t; i < NBK; i += 256) h[i] = 0;
    __syncthreads();
    int base = b * EPB;
    #pragma unroll
    for (int i = 0; i < 16; ++i) {
        int e = base + i * 256 + t;
        if (e < E) atomicAdd(&h[dst[e] >> BKSH], 1);
    }
    __syncthreads();
    for (int i = t; i < NBK; i += 256) ghist[(size_t)i * BLK + b] = h[i];
}

// ---- exclusive scan phases (block-sum add folded into readers) ----
__global__ void gscan1(const int* __restrict__ in, int* __restrict__ out,
                       int* __restrict__ bsums, int M) {
    __shared__ int tmp[256];
    int i = blockIdx.x * 256 + threadIdx.x;
    int v = (i < M) ? in[i] : 0;
    tmp[threadIdx.x] = v; __syncthreads();
    for (int off = 1; off < 256; off <<= 1) {
        int t = (threadIdx.x >= off) ? tmp[threadIdx.x - off] : 0;
        __syncthreads();
        tmp[threadIdx.x] += t;
        __syncthreads();
    }
    if (i < M) out[i] = tmp[threadIdx.x] - v;
    if (threadIdx.x == 255) bsums[blockIdx.x] = tmp[255];
}

__global__ void gscan2(int* __restrict__ bsums, int nb) {   // 1 block, 1024 thr
    __shared__ int tmp[1024];
    int v = (threadIdx.x < nb) ? bsums[threadIdx.x] : 0;
    tmp[threadIdx.x] = v; __syncthreads();
    for (int off = 1; off < 1024; off <<= 1) {
        int t = (threadIdx.x >= off) ? tmp[threadIdx.x - off] : 0;
        __syncthreads();
        tmp[threadIdx.x] += t;
        __syncthreads();
    }
    if (threadIdx.x < nb) bsums[threadIdx.x] = tmp[threadIdx.x] - v;
}

// ---- scatter edges into bucket-sorted tmp (offsets = goff + gbsums) ----
__global__ void bscatter(const int* __restrict__ src, const int* __restrict__ dst,
                         const int* __restrict__ goff, const int* __restrict__ gbsums,
                         uint2* __restrict__ tmp, int E, int NBK, int BLK) {
    __shared__ int off[512];
    int t = threadIdx.x, b = blockIdx.x;
    for (int i = t; i < NBK; i += 256) {
        size_t m = (size_t)i * BLK + b;
        off[i] = goff[m] + gbsums[m >> 8];
    }
    __syncthreads();
    int base = b * EPB;
    #pragma unroll
    for (int i = 0; i < 16; ++i) {
        int e = base + i * 256 + t;
        if (e < E) {
            int d = dst[e];
            int p = atomicAdd(&off[d >> BKSH], 1);   // LDS-local
            tmp[p] = make_uint2((unsigned)src[e], (unsigned)d);
        }
    }
}

// ---- per-bucket: count + LDS scan -> rowptr + dinv ----
__global__ void bucketA(const uint2* __restrict__ tmp, const int* __restrict__ goff,
                        const int* __restrict__ gbsums, int* __restrict__ rowptr,
                        float* __restrict__ dinv, int N, int NBK, int BLK, int E) {
    __shared__ int lc[256], sc[256];
    int b = blockIdx.x, t = threadIdx.x;
    lc[t] = 0; __syncthreads();
    size_t m0 = (size_t)b * BLK;
    int p0 = goff[m0] + gbsums[m0 >> 8];
    int p1 = E;
    if (b + 1 < NBK) { size_t m1 = (size_t)(b + 1) * BLK; p1 = goff[m1] + gbsums[m1 >> 8]; }
    for (int p = p0 + t; p < p1; p += 256) atomicAdd(&lc[tmp[p].y & 255], 1);
    __syncthreads();
    int v = lc[t];
    sc[t] = v; __syncthreads();
    for (int off = 1; off < 256; off <<= 1) {
        int tv = (t >= off) ? sc[t - off] : 0;
        __syncthreads();
        sc[t] += tv;
        __syncthreads();
    }
    int node = (b << BKSH) + t;
    if (node < N) {
        rowptr[node] = p0 + (sc[t] - v);
        dinv[node]   = rsqrtf((float)(v + 1));
    }
    if (b == 0 && t == 0) rowptr[N] = E;
}

// ---- place edges (dense window) + fused layer-1 aggregation ----
__global__ void fillB(const uint2* __restrict__ tmp, const int* __restrict__ goff,
                      const int* __restrict__ gbsums, const int* __restrict__ rowptr,
                      const float* __restrict__ dinv, const float* __restrict__ x,
                      float2* __restrict__ ew, float4* __restrict__ a1,
                      int N, int NBK, int BLK, int E) {
    __shared__ int   lfill[256];
    __shared__ int   rbase[257];
    __shared__ float ldv[256];
    int b = blockIdx.x, t = threadIdx.x;
    int node0 = b << BKSH;
    lfill[t] = 0;
    int node = node0 + t;
    rbase[t] = rowptr[min(node, N)];
    ldv[t]   = dinv[min(node, N - 1)];
    if (t == 0) rbase[256] = rowptr[min(node0 + 256, N)];
    __syncthreads();
    size_t m0 = (size_t)b * BLK;
    int p0 = goff[m0] + gbsums[m0 >> 8];
    int p1 = E;
    if (b + 1 < NBK) { size_t m1 = (size_t)(b + 1) * BLK; p1 = goff[m1] + gbsums[m1 >> 8]; }
    for (int p = p0 + t; p < p1; p += 256) {
        uint2 e = tmp[p];
        int s = (int)e.x, dl = (int)(e.y & 255);
        float w = dinv[s] * ldv[dl];
        int pos = rbase[dl] + atomicAdd(&lfill[dl], 1);
        ew[pos] = make_float2(__int_as_float(s), w);
    }
    __syncthreads();
    // fused agg3: 16 lane-groups sweep the bucket's 256 nodes (ew L2-hot)
    int grp = t >> 4, sub = t & 15;
    for (int ni = grp; ni < 256; ni += 16) {
        int n = node0 + ni;
        if (n >= N) break;
        int q0 = rbase[ni], q1 = rbase[ni + 1];
        float ax = 0.f, ay = 0.f, az = 0.f;
        for (int p = q0 + sub; p < q1; p += 16) {
            float2 e = ew[p];
            int s = __float_as_int(e.x);
            ax = fmaf(e.y, x[s*3+0], ax);
            ay = fmaf(e.y, x[s*3+1], ay);
            az = fmaf(e.y, x[s*3+2], az);
        }
        #pragma unroll
        for (int off = 8; off; off >>= 1) {
            ax += __shfl_down(ax, off, 16);
            ay += __shfl_down(ay, off, 16);
            az += __shfl_down(az, off, 16);
        }
        if (sub == 0) {
            float dv = ldv[ni], sw = dv * dv;
            a1[n] = make_float4(fmaf(sw, x[n*3+0], ax),
                                fmaf(sw, x[n*3+1], ay),
                                fmaf(sw, x[n*3+2], az), sw);
        }
    }
}

// wc[k] = W3[k][:] @ Wh; wc[64] = b3 @ Wh + bh
__global__ void fold_head(const float* __restrict__ W3, const float* __restrict__ b3,
                          const float* __restrict__ Wh, const float* __restrict__ bh,
                          float* __restrict__ wc) {
    int k = threadIdx.x;              // 64
    float acc = 0.0f;
    for (int f = 0; f < 64; f++) acc += W3[k*64+f] * Wh[f];
    wc[k] = acc;
    if (k == 0) {
        float bb = bh[0];
        for (int f = 0; f < 64; f++) bb += b3[f] * Wh[f];
        wc[64] = bb;
    }
}

// z[n] = relu( (S relu(a1@W1+b1))[n] @ W2 + b2 ) @ wc
__global__ void fused_l2l3(const float2* __restrict__ ew, const int* __restrict__ rowptr,
                           const float4* __restrict__ a1, const float* __restrict__ W1,
                           const float* __restrict__ b1, const float* __restrict__ W2,
                           const float* __restrict__ b2, const float* __restrict__ wc,
                           float* __restrict__ z, int N, int E) {
    __shared__ float  Wl[64*64];
    __shared__ float4 pay[4][64];       // wave-private payload chunk
    __shared__ float  a2buf[4][4][64];  // wave-private a2, 4 nodes per batch
    const int tid = threadIdx.x;
    for (int i = tid; i < 4096; i += 256) Wl[i] = W2[i];
    const int lane = tid & 63;
    const int wv   = tid >> 6;
    const float w10 = W1[lane], w11 = W1[64+lane], w12 = W1[128+lane];
    const float b1f = b1[lane], b2f = b2[lane], wcf = wc[lane];
    const int NPW = 8;
    const int n0 = (blockIdx.x * 4 + wv) * NPW;
    int   rpl = rowptr[min(n0 + lane, N)];         // lanes 0..8 used; clamps to E
    float4 sg = a1[min(n0 + lane, N - 1)];         // lanes 0..7 (self terms)
    __syncthreads();
    if (n0 >= N) return;                           // after barrier: safe
    for (int b4 = 0; b4 < 2; ++b4) {
        // ---- edge phase: 4 nodes, acc -> a2buf ----
        for (int k = 0; k < 4; ++k) {
            int cur = b4 * 4 + k;
            int p0 = rfl(__shfl(rpl, cur));
            int p1 = rfl(__shfl(rpl, cur + 1));    // invalid node => p0==p1==E
            float sx = rlane(sg.x, cur), sy = rlane(sg.y, cur);
            float sz2 = rlane(sg.z, cur), sw = rlane(sg.w, cur);
            float ts = fmaf(sz2, w12, fmaf(sy, w11, fmaf(sx, w10, b1f)));
            float acc = sw * fmaxf(ts, 0.f);
            for (int pc = p0; pc < p1; pc += 64) {
                int pidx = pc + lane; if (pidx >= p1) pidx = p1 - 1;
                float2 e = ew[pidx];                       // coalesced per-lane
                float4 g = a1[__float_as_int(e.x)];        // 64-wide gather
                pay[wv][lane] = make_float4(g.x, g.y, g.z, e.y);   // ds_write_b128
                int m = p1 - pc; if (m > 64) m = 64;       // uniform (SGPR)
                const float4* pp = (const float4*)&pay[wv][0];
                int j = 0;
                for (; j + 3 < m; j += 4) {                // uniform ds_read_b128 bcast
                    float4 P0 = pp[j], P1 = pp[j+1], P2 = pp[j+2], P3 = pp[j+3];
                    float t0 = fmaf(P0.z, w12, fmaf(P0.y, w11, fmaf(P0.x, w10, b1f)));
                    float t1 = fmaf(P1.z, w12, fmaf(P1.y, w11, fmaf(P1.x, w10, b1f)));
                    float t2 = fmaf(P2.z, w12, fmaf(P2.y, w11, fmaf(P2.x, w10, b1f)));
                    float t3 = fmaf(P3.z, w12, fmaf(P3.y, w11, fmaf(P3.x, w10, b1f)));
                    acc = fmaf(P0.w, fmaxf(t0, 0.f), acc);
                    acc = fmaf(P1.w, fmaxf(t1, 0.f), acc);
                    acc = fmaf(P2.w, fmaxf(t2, 0.f), acc);
                    acc = fmaf(P3.w, fmaxf(t3, 0.f), acc);
                }
                for (; j < m; ++j) {
                    float4 P = pp[j];
                    float tt = fmaf(P.z, w12, fmaf(P.y, w11, fmaf(P.x, w10, b1f)));
                    acc = fmaf(P.w, fmaxf(tt, 0.f), acc);
                }
            }
            a2buf[wv][k][lane] = acc;
        }
        // ---- stage B: batched W2 matmul, NAMED scalars only ----
        float h0 = b2f, h1 = b2f, h2 = b2f, h3 = b2f;
        const float4* a4p = (const float4*)&a2buf[wv][0][0];   // [4][16] float4
        #pragma unroll
        for (int k4 = 0; k4 < 16; ++k4) {
            float wk0 = Wl[(4*k4+0)*64 + lane];    // stride-1, conflict-free
            float wk1 = Wl[(4*k4+1)*64 + lane];
            float wk2 = Wl[(4*k4+2)*64 + lane];
            float wk3 = Wl[(4*k4+3)*64 + lane];
            float4 aa0 = a4p[0*16 + k4];           // uniform b128 broadcast
            float4 aa1 = a4p[1*16 + k4];
            float4 aa2 = a4p[2*16 + k4];
            float4 aa3 = a4p[3*16 + k4];
            h0 = fmaf(aa0.x, wk0, h0); h0 = fmaf(aa0.y, wk1, h0);
            h0 = fmaf(aa0.z, wk2, h0); h0 = fmaf(aa0.w, wk3, h0);
            h1 = fmaf(aa1.x, wk0, h1); h1 = fmaf(aa1.y, wk1, h1);
            h1 = fmaf(aa1.z, wk2, h1); h1 = fmaf(aa1.w, wk3, h1);
            h2 = fmaf(aa2.x, wk0, h2); h2 = fmaf(aa2.y, wk1, h2);
            h2 = fmaf(aa2.z, wk2, h2); h2 = fmaf(aa2.w, wk3, h2);
            h3 = fmaf(aa3.x, wk0, h3); h3 = fmaf(aa3.y, wk1, h3);
            h3 = fmaf(aa3.z, wk2, h3); h3 = fmaf(aa3.w, wk3, h3);
        }
        int nb = n0 + b4 * 4;                      // explicit per-node epilogues
        {
            float v = fmaxf(h0, 0.f) * wcf;
            #pragma unroll
            for (int off = 32; off; off >>= 1) v += __shfl_down(v, off);
            if (lane == 0 && nb + 0 < N) z[nb + 0] = v;
        }
        {
            float v = fmaxf(h1, 0.f) * wcf;
            #pragma unroll
            for (int off = 32; off; off >>= 1) v += __shfl_down(v, off);
            if (lane == 0 && nb + 1 < N) z[nb + 1] = v;
        }
        {
            float v = fmaxf(h2, 0.f) * wcf;
            #pragma unroll
            for (int off = 32; off; off >>= 1) v += __shfl_down(v, off);
            if (lane == 0 && nb + 2 < N) z[nb + 2] = v;
        }
        {
            float v = fmaxf(h3, 0.f) * wcf;
            #pragma unroll
            for (int off = 32; off; off >>= 1) v += __shfl_down(v, off);
            if (lane == 0 && nb + 3 < N) z[nb + 3] = v;
        }
    }
}

// logits[n] = dinv^2 z[n] + sum_e w z[s] + c; 16-lane group per node
__global__ void final_wave(const float* __restrict__ z, const float2* __restrict__ ew,
                           const int* __restrict__ rowptr, const float* __restrict__ dinv,
                           const float* __restrict__ wc, float* __restrict__ out, int N) {
    int g   = (blockIdx.x * blockDim.x + threadIdx.x) >> 4;
    int sub = threadIdx.x & 15;
    if (g >= N) return;
    int p0 = rowptr[g], p1 = rowptr[g+1];
    float acc = 0.f;
    for (int p = p0 + sub; p < p1; p += 16) {
        float2 e = ew[p];
        acc = fmaf(e.y, z[__float_as_int(e.x)], acc);
    }
    #pragma unroll
    for (int off = 8; off; off >>= 1) acc += __shfl_down(acc, off, 16);
    if (sub == 0) {
        float dv = dinv[g];
        out[g] = fmaf(dv * dv, z[g], acc) + wc[64];
    }
}

extern "C" void kernel_launch(void* const* d_in, const int* in_sizes, int n_in,
                              void* d_out, int out_size, void* d_ws, size_t ws_size,
                              hipStream_t stream) {
    const float* x   = (const float*)d_in[0];
    const int*   ei  = (const int*)d_in[1];
    const float* W1  = (const float*)d_in[2];
    const float* b1  = (const float*)d_in[3];
    const float* W2  = (const float*)d_in[4];
    const float* b2  = (const float*)d_in[5];
    const float* W3  = (const float*)d_in[6];
    const float* b3  = (const float*)d_in[7];
    const float* Wh  = (const float*)d_in[8];
    const float* bh  = (const float*)d_in[9];
    float* logits = (float*)d_out;

    const int N = in_sizes[0] / 3;
    const int E = in_sizes[1] / 2;
    const int* src = ei;
    const int* dst = ei + E;

    const int NBK = (N + 255) >> BKSH;            // 391 buckets
    const int BLK = (E + EPB - 1) / EPB;          // 391 scatter blocks
    const int M   = NBK * BLK;

    float* base = (float*)d_ws;
    size_t o = 0;
    float*  dinv   = base + o; o += (size_t)N;
    o = (o + 3) & ~(size_t)3;
    float4* a1     = (float4*)(base + o); o += (size_t)4*N;
    int*    rowptr = (int*)(base + o); o += (size_t)N + 1;
    int*    gbsums = (int*)(base + o); o += 1024;
    o = (o + 1) & ~(size_t)1;
    float2* ew     = (float2*)(base + o); o += (size_t)2*E;
    uint2*  tmpb   = (uint2*)(base + o); o += (size_t)2*E;
    float*  zbuf   = base + o; o += (size_t)N;
    float*  wc     = base + o; o += 65;
    int*    ghist  = (int*)(base + o); o += (size_t)M;
    int*    goff   = (int*)(base + o); o += (size_t)M;

    const int BS = 256;
    int gM   = (M + BS - 1) / BS;
    int g16  = ((size_t)N * 16 + BS - 1) / BS;
    int gFU  = (N + 31) / 32;

    bhist    <<<BLK, BS, 0, stream>>>(dst, ghist, E, NBK, BLK);
    gscan1   <<<gM,  BS, 0, stream>>>(ghist, goff, gbsums, M);
    gscan2   <<<1, 1024, 0, stream>>>(gbsums, gM);
    bscatter <<<BLK, BS, 0, stream>>>(src, dst, goff, gbsums, tmpb, E, NBK, BLK);
    bucketA  <<<NBK, BS, 0, stream>>>(tmpb, goff, gbsums, rowptr, dinv, N, NBK, BLK, E);
    fillB    <<<NBK, BS, 0, stream>>>(tmpb, goff, gbsums, rowptr, dinv, x, ew, a1, N, NBK, BLK, E);

    fold_head  <<<1, 64, 0, stream>>>(W3, b3, Wh, bh, wc);
    fused_l2l3 <<<gFU, BS, 0, stream>>>(ew, rowptr, a1, W1, b1, W2, b2, wc, zbuf, N, E);
    final_wave <<<g16, BS, 0, stream>>>(zbuf, ew, rowptr, dinv, wc, logits, N);
}

// Round 15
// 164.552 us; speedup vs baseline: 5.7655x; 3.0087x over previous
//
#include <hip/hip_runtime.h>

// GCN 3-layer, R15 = R11 build + R10 fused (per-node epilogue, VGPR-lean)
// with ONE isolated change: edge-loop payload broadcast via wave-private LDS
// (ds_write_b128 + uniform ds_read_b128) instead of 4x v_readlane per edge.
// R12-R14 post-mortem: batched multi-node epilogues (unroll-16 x 4-8 nodes of
// live state) spill to scratch catastrophically -> abandoned.

#define BKSH 8                      // 256 nodes per bucket
#define EPB  4096                   // edges per scatter block

__device__ __forceinline__ float rlane(float v, int l) {
    return __int_as_float(__builtin_amdgcn_readlane(__float_as_int(v), l));
}
__device__ __forceinline__ int rfl(int v) { return __builtin_amdgcn_readfirstlane(v); }

// ---- per-block bucket histogram ----
__global__ void bhist(const int* __restrict__ dst, int* __restrict__ ghist,
                      int E, int NBK, int BLK) {
    __shared__ int h[512];
    int t = threadIdx.x, b = blockIdx.x;
    for (int i = t; i < NBK; i += 256) h[i] = 0;
    __syncthreads();
    int base = b * EPB;
    #pragma unroll
    for (int i = 0; i < 16; ++i) {
        int e = base + i * 256 + t;
        if (e < E) atomicAdd(&h[dst[e] >> BKSH], 1);
    }
    __syncthreads();
    for (int i = t; i < NBK; i += 256) ghist[(size_t)i * BLK + b] = h[i];
}

// ---- exclusive scan phases (block-sum add folded into readers) ----
__global__ void gscan1(const int* __restrict__ in, int* __restrict__ out,
                       int* __restrict__ bsums, int M) {
    __shared__ int tmp[256];
    int i = blockIdx.x * 256 + threadIdx.x;
    int v = (i < M) ? in[i] : 0;
    tmp[threadIdx.x] = v; __syncthreads();
    for (int off = 1; off < 256; off <<= 1) {
        int t = (threadIdx.x >= off) ? tmp[threadIdx.x - off] : 0;
        __syncthreads();
        tmp[threadIdx.x] += t;
        __syncthreads();
    }
    if (i < M) out[i] = tmp[threadIdx.x] - v;
    if (threadIdx.x == 255) bsums[blockIdx.x] = tmp[255];
}

__global__ void gscan2(int* __restrict__ bsums, int nb) {   // 1 block, 1024 thr
    __shared__ int tmp[1024];
    int v = (threadIdx.x < nb) ? bsums[threadIdx.x] : 0;
    tmp[threadIdx.x] = v; __syncthreads();
    for (int off = 1; off < 1024; off <<= 1) {
        int t = (threadIdx.x >= off) ? tmp[threadIdx.x - off] : 0;
        __syncthreads();
        tmp[threadIdx.x] += t;
        __syncthreads();
    }
    if (threadIdx.x < nb) bsums[threadIdx.x] = tmp[threadIdx.x] - v;
}

// ---- scatter edges into bucket-sorted tmp (offsets = goff + gbsums) ----
__global__ void bscatter(const int* __restrict__ src, const int* __restrict__ dst,
                         const int* __restrict__ goff, const int* __restrict__ gbsums,
                         uint2* __restrict__ tmp, int E, int NBK, int BLK) {
    __shared__ int off[512];
    int t = threadIdx.x, b = blockIdx.x;
    for (int i = t; i < NBK; i += 256) {
        size_t m = (size_t)i * BLK + b;
        off[i] = goff[m] + gbsums[m >> 8];
    }
    __syncthreads();
    int base = b * EPB;
    #pragma unroll
    for (int i = 0; i < 16; ++i) {
        int e = base + i * 256 + t;
        if (e < E) {
            int d = dst[e];
            int p = atomicAdd(&off[d >> BKSH], 1);   // LDS-local
            tmp[p] = make_uint2((unsigned)src[e], (unsigned)d);
        }
    }
}

// ---- per-bucket: count + LDS scan -> rowptr + dinv ----
__global__ void bucketA(const uint2* __restrict__ tmp, const int* __restrict__ goff,
                        const int* __restrict__ gbsums, int* __restrict__ rowptr,
                        float* __restrict__ dinv, int N, int NBK, int BLK, int E) {
    __shared__ int lc[256], sc[256];
    int b = blockIdx.x, t = threadIdx.x;
    lc[t] = 0; __syncthreads();
    size_t m0 = (size_t)b * BLK;
    int p0 = goff[m0] + gbsums[m0 >> 8];
    int p1 = E;
    if (b + 1 < NBK) { size_t m1 = (size_t)(b + 1) * BLK; p1 = goff[m1] + gbsums[m1 >> 8]; }
    for (int p = p0 + t; p < p1; p += 256) atomicAdd(&lc[tmp[p].y & 255], 1);
    __syncthreads();
    int v = lc[t];
    sc[t] = v; __syncthreads();
    for (int off = 1; off < 256; off <<= 1) {
        int tv = (t >= off) ? sc[t - off] : 0;
        __syncthreads();
        sc[t] += tv;
        __syncthreads();
    }
    int node = (b << BKSH) + t;
    if (node < N) {
        rowptr[node] = p0 + (sc[t] - v);
        dinv[node]   = rsqrtf((float)(v + 1));
    }
    if (b == 0 && t == 0) rowptr[N] = E;
}

// ---- place edges (dense window) + fused layer-1 aggregation ----
__global__ void fillB(const uint2* __restrict__ tmp, const int* __restrict__ goff,
                      const int* __restrict__ gbsums, const int* __restrict__ rowptr,
                      const float* __restrict__ dinv, const float* __restrict__ x,
                      float2* __restrict__ ew, float4* __restrict__ a1,
                      int N, int NBK, int BLK, int E) {
    __shared__ int   lfill[256];
    __shared__ int   rbase[257];
    __shared__ float ldv[256];
    int b = blockIdx.x, t = threadIdx.x;
    int node0 = b << BKSH;
    lfill[t] = 0;
    int node = node0 + t;
    rbase[t] = rowptr[min(node, N)];
    ldv[t]   = dinv[min(node, N - 1)];
    if (t == 0) rbase[256] = rowptr[min(node0 + 256, N)];
    __syncthreads();
    size_t m0 = (size_t)b * BLK;
    int p0 = goff[m0] + gbsums[m0 >> 8];
    int p1 = E;
    if (b + 1 < NBK) { size_t m1 = (size_t)(b + 1) * BLK; p1 = goff[m1] + gbsums[m1 >> 8]; }
    for (int p = p0 + t; p < p1; p += 256) {
        uint2 e = tmp[p];
        int s = (int)e.x, dl = (int)(e.y & 255);
        float w = dinv[s] * ldv[dl];
        int pos = rbase[dl] + atomicAdd(&lfill[dl], 1);
        ew[pos] = make_float2(__int_as_float(s), w);
    }
    __syncthreads();
    // fused agg3: 16 lane-groups sweep the bucket's 256 nodes (ew L2-hot)
    int grp = t >> 4, sub = t & 15;
    for (int ni = grp; ni < 256; ni += 16) {
        int n = node0 + ni;
        if (n >= N) break;
        int q0 = rbase[ni], q1 = rbase[ni + 1];
        float ax = 0.f, ay = 0.f, az = 0.f;
        for (int p = q0 + sub; p < q1; p += 16) {
            float2 e = ew[p];
            int s = __float_as_int(e.x);
            ax = fmaf(e.y, x[s*3+0], ax);
            ay = fmaf(e.y, x[s*3+1], ay);
            az = fmaf(e.y, x[s*3+2], az);
        }
        #pragma unroll
        for (int off = 8; off; off >>= 1) {
            ax += __shfl_down(ax, off, 16);
            ay += __shfl_down(ay, off, 16);
            az += __shfl_down(az, off, 16);
        }
        if (sub == 0) {
            float dv = ldv[ni], sw = dv * dv;
            a1[n] = make_float4(fmaf(sw, x[n*3+0], ax),
                                fmaf(sw, x[n*3+1], ay),
                                fmaf(sw, x[n*3+2], az), sw);
        }
    }
}

// wc[k] = W3[k][:] @ Wh; wc[64] = b3 @ Wh + bh
__global__ void fold_head(const float* __restrict__ W3, const float* __restrict__ b3,
                          const float* __restrict__ Wh, const float* __restrict__ bh,
                          float* __restrict__ wc) {
    int k = threadIdx.x;              // 64
    float acc = 0.0f;
    for (int f = 0; f < 64; f++) acc += W3[k*64+f] * Wh[f];
    wc[k] = acc;
    if (k == 0) {
        float bb = bh[0];
        for (int f = 0; f < 64; f++) bb += b3[f] * Wh[f];
        wc[64] = bb;
    }
}

// z[n] = relu( (S relu(a1@W1+b1))[n] @ W2 + b2 ) @ wc
// R10 structure; ONLY change: payload broadcast via wave-private LDS.
__global__ void fused_l2l3(const float2* __restrict__ ew, const int* __restrict__ rowptr,
                           const float4* __restrict__ a1, const float* __restrict__ W1,
                           const float* __restrict__ b1, const float* __restrict__ W2,
                           const float* __restrict__ b2, const float* __restrict__ wc,
                           float* __restrict__ z, int N, int E) {
    __shared__ float  Wl[64*64];
    __shared__ float4 pay[4][64];       // wave-private payload chunk
    __shared__ float  a2buf[4][64];
    const int tid = threadIdx.x;
    for (int i = tid; i < 4096; i += 256) Wl[i] = W2[i];
    const int lane = tid & 63;
    const int wv   = tid >> 6;
    const float w10 = W1[lane], w11 = W1[64+lane], w12 = W1[128+lane];
    const float b1f = b1[lane], b2f = b2[lane], wcf = wc[lane];
    const int NPW = 8;
    const int n0 = (blockIdx.x * 4 + wv) * NPW;
    int   rpl = rowptr[min(n0 + lane, N)];         // lanes 0..8 used
    float4 sg = a1[min(n0 + lane, N - 1)];         // lanes 0..7 used (self terms)
    __syncthreads();
    if (n0 >= N) return;                           // after barrier: safe
    for (int cur = 0; cur < NPW; ++cur) {
        int n = n0 + cur;
        if (n >= N) break;
        int p0 = rfl(__shfl(rpl, cur));
        int p1 = rfl(__shfl(rpl, cur + 1));
        float sx = rlane(sg.x, cur), sy = rlane(sg.y, cur);
        float sz2 = rlane(sg.z, cur), sw = rlane(sg.w, cur);
        float ts = fmaf(sz2, w12, fmaf(sy, w11, fmaf(sx, w10, b1f)));
        float acc = sw * fmaxf(ts, 0.f);
        for (int pc = p0; pc < p1; pc += 64) {
            int pidx = pc + lane; if (pidx >= p1) pidx = p1 - 1;
            float2 e = ew[pidx];                       // coalesced per-lane
            float4 g = a1[__float_as_int(e.x)];        // 64-wide gather
            pay[wv][lane] = make_float4(g.x, g.y, g.z, e.y);   // ds_write_b128
            int m = p1 - pc; if (m > 64) m = 64;       // uniform trip (SGPR)
            const float4* pp = (const float4*)&pay[wv][0];
            int j = 0;
            for (; j + 3 < m; j += 4) {                // uniform ds_read_b128 bcast
                float4 P0 = pp[j], P1 = pp[j+1], P2 = pp[j+2], P3 = pp[j+3];
                float t0 = fmaf(P0.z, w12, fmaf(P0.y, w11, fmaf(P0.x, w10, b1f)));
                float t1 = fmaf(P1.z, w12, fmaf(P1.y, w11, fmaf(P1.x, w10, b1f)));
                float t2 = fmaf(P2.z, w12, fmaf(P2.y, w11, fmaf(P2.x, w10, b1f)));
                float t3 = fmaf(P3.z, w12, fmaf(P3.y, w11, fmaf(P3.x, w10, b1f)));
                acc = fmaf(P0.w, fmaxf(t0, 0.f), acc);
                acc = fmaf(P1.w, fmaxf(t1, 0.f), acc);
                acc = fmaf(P2.w, fmaxf(t2, 0.f), acc);
                acc = fmaf(P3.w, fmaxf(t3, 0.f), acc);
            }
            for (; j < m; ++j) {
                float4 P = pp[j];
                float tt = fmaf(P.z, w12, fmaf(P.y, w11, fmaf(P.x, w10, b1f)));
                acc = fmaf(P.w, fmaxf(tt, 0.f), acc);
            }
        }
        // a2 exchange (wave-private LDS row), then W2 matmul from LDS (R10 proven)
        a2buf[wv][lane] = acc;
        float h = b2f;
        const float4* a4 = (const float4*)&a2buf[wv][0];
        #pragma unroll
        for (int k4 = 0; k4 < 16; ++k4) {
            float4 a = a4[k4];                     // uniform broadcast read
            h = fmaf(a.x, Wl[(4*k4+0)*64 + lane], h);
            h = fmaf(a.y, Wl[(4*k4+1)*64 + lane], h);
            h = fmaf(a.z, Wl[(4*k4+2)*64 + lane], h);
            h = fmaf(a.w, Wl[(4*k4+3)*64 + lane], h);
        }
        float v = fmaxf(h, 0.f) * wcf;
        #pragma unroll
        for (int off = 32; off; off >>= 1) v += __shfl_down(v, off);
        if (lane == 0) z[n] = v;
    }
}

// logits[n] = dinv^2 z[n] + sum_e w z[s] + c; 16-lane group per node
__global__ void final_wave(const float* __restrict__ z, const float2* __restrict__ ew,
                           const int* __restrict__ rowptr, const float* __restrict__ dinv,
                           const float* __restrict__ wc, float* __restrict__ out, int N) {
    int g   = (blockIdx.x * blockDim.x + threadIdx.x) >> 4;
    int sub = threadIdx.x & 15;
    if (g >= N) return;
    int p0 = rowptr[g], p1 = rowptr[g+1];
    float acc = 0.f;
    for (int p = p0 + sub; p < p1; p += 16) {
        float2 e = ew[p];
        acc = fmaf(e.y, z[__float_as_int(e.x)], acc);
    }
    #pragma unroll
    for (int off = 8; off; off >>= 1) acc += __shfl_down(acc, off, 16);
    if (sub == 0) {
        float dv = dinv[g];
        out[g] = fmaf(dv * dv, z[g], acc) + wc[64];
    }
}

extern "C" void kernel_launch(void* const* d_in, const int* in_sizes, int n_in,
                              void* d_out, int out_size, void* d_ws, size_t ws_size,
                              hipStream_t stream) {
    const float* x   = (const float*)d_in[0];
    const int*   ei  = (const int*)d_in[1];
    const float* W1  = (const float*)d_in[2];
    const float* b1  = (const float*)d_in[3];
    const float* W2  = (const float*)d_in[4];
    const float* b2  = (const float*)d_in[5];
    const float* W3  = (const float*)d_in[6];
    const float* b3  = (const float*)d_in[7];
    const float* Wh  = (const float*)d_in[8];
    const float* bh  = (const float*)d_in[9];
    float* logits = (float*)d_out;

    const int N = in_sizes[0] / 3;
    const int E = in_sizes[1] / 2;
    const int* src = ei;
    const int* dst = ei + E;

    const int NBK = (N + 255) >> BKSH;            // 391 buckets
    const int BLK = (E + EPB - 1) / EPB;          // 391 scatter blocks
    const int M   = NBK * BLK;

    float* base = (float*)d_ws;
    size_t o = 0;
    float*  dinv   = base + o; o += (size_t)N;
    o = (o + 3) & ~(size_t)3;
    float4* a1     = (float4*)(base + o); o += (size_t)4*N;
    int*    rowptr = (int*)(base + o); o += (size_t)N + 1;
    int*    gbsums = (int*)(base + o); o += 1024;
    o = (o + 1) & ~(size_t)1;
    float2* ew     = (float2*)(base + o); o += (size_t)2*E;
    uint2*  tmpb   = (uint2*)(base + o); o += (size_t)2*E;
    float*  zbuf   = base + o; o += (size_t)N;
    float*  wc     = base + o; o += 65;
    int*    ghist  = (int*)(base + o); o += (size_t)M;
    int*    goff   = (int*)(base + o); o += (size_t)M;

    const int BS = 256;
    int gM   = (M + BS - 1) / BS;
    int g16  = ((size_t)N * 16 + BS - 1) / BS;
    int gFU  = (N + 31) / 32;

    bhist    <<<BLK, BS, 0, stream>>>(dst, ghist, E, NBK, BLK);
    gscan1   <<<gM,  BS, 0, stream>>>(ghist, goff, gbsums, M);
    gscan2   <<<1, 1024, 0, stream>>>(gbsums, gM);
    bscatter <<<BLK, BS, 0, stream>>>(src, dst, goff, gbsums, tmpb, E, NBK, BLK);
    bucketA  <<<NBK, BS, 0, stream>>>(tmpb, goff, gbsums, rowptr, dinv, N, NBK, BLK, E);
    fillB    <<<NBK, BS, 0, stream>>>(tmpb, goff, gbsums, rowptr, dinv, x, ew, a1, N, NBK, BLK, E);

    fold_head  <<<1, 64, 0, stream>>>(W3, b3, Wh, bh, wc);
    fused_l2l3 <<<gFU, BS, 0, stream>>>(ew, rowptr, a1, W1, b1, W2, b2, wc, zbuf, N, E);
    final_wave <<<g16, BS, 0, stream>>>(zbuf, ew, rowptr, dinv, wc, logits, N);
}